// Round 3
// baseline (5910.292 us; speedup 1.0000x reference)
//
#include <hip/hip_runtime.h>
#include <stdint.h>

// Problem dims
#define NB   64      // batch
#define NT   256     // timesteps
#define NS   512     // input feature (state)
#define NH   1024    // hidden
#define NG   4096    // 4*NH (gates)
#define NHD  512     // dense1 width
#define NA   64      // action size
#define NO   64      // n_output

typedef float f32x4  __attribute__((ext_vector_type(4)));
typedef short bf16x8 __attribute__((ext_vector_type(8)));

__device__ __forceinline__ unsigned short f2bf(float f) {
    union { float f; unsigned u; } a; a.f = f;
    unsigned u = a.u;
    return (unsigned short)((u + 0x7fffu + ((u >> 16) & 1u)) >> 16);   // RNE
}
__device__ __forceinline__ float bf2f(unsigned short h) {
    union { unsigned u; float f; } a; a.u = ((unsigned)h) << 16; return a.f;
}
__device__ __forceinline__ float sigm(float x) { return 1.0f / (1.0f + expf(-x)); }

// Workspace layout (bytes):
//   [0)       hhi : 2 x 64 x 1024 bf16 = 262144   (h high bf16, double-buffered)
//   [262144)  hlo : 2 x 64 x 1024 bf16 = 262144   (h residual bf16)
//   [524288)  hF32: 64 x 1024 f32      = 262144
//   [786432)  hid : 64 x 512 f32       = 131072
//   [917504)  ctr : 256 ints           = 1024
#define WS_HHI   0
#define WS_HLO   262144
#define WS_HF32  524288
#define WS_HID   786432
#define WS_CTR   917504

__global__ void prologue(unsigned int* __restrict__ hhi32,
                         unsigned int* __restrict__ hlo32,
                         unsigned int* __restrict__ ctr32) {
    int idx = blockIdx.x * blockDim.x + threadIdx.x;   // 65536 threads
    hhi32[idx] = 0u;                                    // zero both parities
    hlo32[idx] = 0u;
    if (idx < 256) ctr32[idx] = 0u;
}

// Persistent LSTM recurrence, double-bf16 (hi/lo) precision.
// PLAIN launch (cooperative launch fails silently in this harness — r2 post-mortem:
// absmax bit-identical across precision overhaul => lstm never ran).
// 256 blocks == 256 CUs, 1 block/CU via __launch_bounds__(256,1): all blocks
// co-resident under CP round-robin dispatch => group spin-barrier is safe.
// Grid: 256 blocks x 256 threads; 2 groups x 128 blocks.
//   group g: batches [32g, 32g+32)  (2 MFMA m-tiles of 16)
//   block bi in group: h-cols [8bi, 8bi+8), all 4 gates -> 32 z-cols
//     packed as 2 MFMA n-tiles: nt, n(0..15): gate = nt*2 + (n>>3), col = 8bi + (n&7)
//   wave w: K-slices x:[128w,128w+128) (4 ksteps), h:[256w,256w+256) (8 ksteps)
// Each fp32 value v = hi + lo (two bf16); tile product = 3 MFMAs (hh, hl, lh).
__global__ __launch_bounds__(256, 1) void lstm_persist(
    const float* __restrict__ x, const float* __restrict__ Wx,
    const float* __restrict__ Wh, const float* __restrict__ bias,
    unsigned short* __restrict__ hhi, unsigned short* __restrict__ hlo,
    float* __restrict__ hF32, int* __restrict__ ctr)
{
    const int g    = blockIdx.x >> 7;
    const int bi   = blockIdx.x & 127;
    const int tid  = threadIdx.x;
    const int w    = tid >> 6;
    const int lane = tid & 63;
    const int lm   = lane & 15;   // A: m(batch row) ; B: n ; D: col
    const int lq   = lane >> 4;   // k-quad

    __shared__ float zl[4][2][2][16][17];   // [wave][mt][nt][row][col] (+1 pad)

    // ---- one-time: weight B-fragments (hi/lo bf16) into registers ----
    // B-frag (16x16x32): lane holds B[k = lq*8 + j][n = lm], j = 0..7
    bf16x8 wxh[2][4], wxl[2][4];   // [nt][kstep] x-path, K=512/4waves
    bf16x8 whh[2][8], whl[2][8];   // [nt][kstep] h-path, K=1024/4waves
    #pragma unroll
    for (int nt = 0; nt < 2; ++nt) {
        const int gate = nt * 2 + (lm >> 3);
        const int zc   = gate * NH + bi * 8 + (lm & 7);
        #pragma unroll
        for (int ks = 0; ks < 4; ++ks)
            #pragma unroll
            for (int j = 0; j < 8; ++j) {
                int k = w * 128 + ks * 32 + lq * 8 + j;
                float v = Wx[(size_t)k * NG + zc];
                unsigned short h = f2bf(v);
                wxh[nt][ks][j] = (short)h;
                wxl[nt][ks][j] = (short)f2bf(v - bf2f(h));
            }
        #pragma unroll
        for (int ks = 0; ks < 8; ++ks)
            #pragma unroll
            for (int j = 0; j < 8; ++j) {
                int k = w * 256 + ks * 32 + lq * 8 + j;
                float v = Wh[(size_t)k * NG + zc];
                unsigned short h = f2bf(v);
                whh[nt][ks][j] = (short)h;
                whl[nt][ks][j] = (short)f2bf(v - bf2f(h));
            }
    }

    // ---- per-thread cell state: thread owns (batch, h-col) ----
    const int bloc   = tid >> 3;         // batch-in-group 0..31
    const int hcc    = tid & 7;          // h-col-in-block 0..7
    const int gbatch = g * 32 + bloc;
    const int col    = bi * 8 + hcc;
    const int emt    = bloc >> 4;        // m-tile for LDS read
    const int emr    = bloc & 15;        // row within m-tile
    float bgate[4];
    #pragma unroll
    for (int gt = 0; gt < 4; ++gt) bgate[gt] = bias[gt * NH + col];
    float c = 0.0f;

    int* const myctr = &ctr[g * 64];

    #pragma unroll 1
    for (int t = 0; t < NT; ++t) {
        const size_t par = (size_t)(t & 1) * (NB * NH);

        // ---- h A-fragments (hi+lo), both m-tiles — issue loads early ----
        bf16x8 ahh[2][8], ahl[2][8];
        #pragma unroll
        for (int mt = 0; mt < 2; ++mt) {
            const size_t rb = par + (size_t)(g * 32 + mt * 16 + lm) * NH + w * 256 + lq * 8;
            #pragma unroll
            for (int ks = 0; ks < 8; ++ks) {
                ahh[mt][ks] = *reinterpret_cast<const bf16x8*>(hhi + rb + ks * 32);
                ahl[mt][ks] = *reinterpret_cast<const bf16x8*>(hlo + rb + ks * 32);
            }
        }

        f32x4 acc[2][2];
        #pragma unroll
        for (int mt = 0; mt < 2; ++mt)
            #pragma unroll
            for (int nt = 0; nt < 2; ++nt) {
                acc[mt][nt][0] = 0.f; acc[mt][nt][1] = 0.f;
                acc[mt][nt][2] = 0.f; acc[mt][nt][3] = 0.f;
            }

        // ---- x path: load fp32, split hi/lo, 3-term MFMA ----
        #pragma unroll
        for (int ks = 0; ks < 4; ++ks) {
            bf16x8 axh[2], axl[2];
            #pragma unroll
            for (int mt = 0; mt < 2; ++mt) {
                const float* xs = x + ((size_t)(g * 32 + mt * 16 + lm) * NT + t) * NS
                                    + w * 128 + ks * 32 + lq * 8;
                const f32x4* p = reinterpret_cast<const f32x4*>(xs);
                f32x4 vlo = p[0], vhi = p[1];
                #pragma unroll
                for (int j = 0; j < 4; ++j) {
                    unsigned short h0 = f2bf(vlo[j]);
                    axh[mt][j]     = (short)h0;
                    axl[mt][j]     = (short)f2bf(vlo[j] - bf2f(h0));
                    unsigned short h1 = f2bf(vhi[j]);
                    axh[mt][4 + j] = (short)h1;
                    axl[mt][4 + j] = (short)f2bf(vhi[j] - bf2f(h1));
                }
            }
            #pragma unroll
            for (int mt = 0; mt < 2; ++mt)
                #pragma unroll
                for (int nt = 0; nt < 2; ++nt) {
                    acc[mt][nt] = __builtin_amdgcn_mfma_f32_16x16x32_bf16(axh[mt], wxh[nt][ks], acc[mt][nt], 0, 0, 0);
                    acc[mt][nt] = __builtin_amdgcn_mfma_f32_16x16x32_bf16(axh[mt], wxl[nt][ks], acc[mt][nt], 0, 0, 0);
                    acc[mt][nt] = __builtin_amdgcn_mfma_f32_16x16x32_bf16(axl[mt], wxh[nt][ks], acc[mt][nt], 0, 0, 0);
                }
        }

        // ---- h path: 3-term MFMA ----
        #pragma unroll
        for (int ks = 0; ks < 8; ++ks)
            #pragma unroll
            for (int mt = 0; mt < 2; ++mt)
                #pragma unroll
                for (int nt = 0; nt < 2; ++nt) {
                    acc[mt][nt] = __builtin_amdgcn_mfma_f32_16x16x32_bf16(ahh[mt][ks], whh[nt][ks], acc[mt][nt], 0, 0, 0);
                    acc[mt][nt] = __builtin_amdgcn_mfma_f32_16x16x32_bf16(ahh[mt][ks], whl[nt][ks], acc[mt][nt], 0, 0, 0);
                    acc[mt][nt] = __builtin_amdgcn_mfma_f32_16x16x32_bf16(ahl[mt][ks], whh[nt][ks], acc[mt][nt], 0, 0, 0);
                }

        // ---- cross-wave K-reduction via LDS ----
        // D layout: row = lq*4 + r, col = lm
        #pragma unroll
        for (int mt = 0; mt < 2; ++mt)
            #pragma unroll
            for (int nt = 0; nt < 2; ++nt)
                #pragma unroll
                for (int r = 0; r < 4; ++r)
                    zl[w][mt][nt][lq * 4 + r][lm] = acc[mt][nt][r];
        __syncthreads();

        float zg[4];
        #pragma unroll
        for (int gt = 0; gt < 4; ++gt) {
            const int nt = gt >> 1;
            const int n  = (gt & 1) * 8 + hcc;
            zg[gt] = zl[0][emt][nt][emr][n] + zl[1][emt][nt][emr][n]
                   + zl[2][emt][nt][emr][n] + zl[3][emt][nt][emr][n] + bgate[gt];
        }

        // Keras gate order: i, f, g, o
        float ig = sigm(zg[0]);
        float fg = sigm(zg[1]);
        float gg = tanhf(zg[2]);
        float og = sigm(zg[3]);
        c = fg * c + ig * gg;
        float hv = og * tanhf(c);

        unsigned short hb = f2bf(hv);
        const size_t po = (size_t)((t + 1) & 1) * (NB * NH) + (size_t)gbatch * NH + col;
        hhi[po] = hb;
        hlo[po] = f2bf(hv - bf2f(hb));
        if (t == NT - 1) hF32[(size_t)gbatch * NH + col] = hv;

        // ---- group barrier (cross-XCD) ----
        // syncthreads drains all waves' stores into L2; tid0's RELEASE add
        // performs the XCD L2 writeback; relaxed agent spin; acquire fence
        // (__threadfence) invalidates stale L1/L2 before next step's h reads.
        __syncthreads();
        if (tid == 0) {
            __hip_atomic_fetch_add(myctr, 1, __ATOMIC_RELEASE, __HIP_MEMORY_SCOPE_AGENT);
            const int target = 128 * (t + 1);
            while (__hip_atomic_load(myctr, __ATOMIC_RELAXED, __HIP_MEMORY_SCOPE_AGENT) < target)
                __builtin_amdgcn_s_sleep(2);
            __threadfence();
        }
        __syncthreads();
    }
}

// hid = relu(hF32 @ Wd1 + bd1)   [64,1024]x[1024,512]
__global__ void head1(const float* __restrict__ hF32, const float* __restrict__ Wd1,
                      const float* __restrict__ bd1, float* __restrict__ hid)
{
    int b = blockIdx.x >> 1;
    int n = (blockIdx.x & 1) * 256 + threadIdx.x;
    const float* hrow = hF32 + (size_t)b * NH;
    float acc = bd1[n];
    #pragma unroll 4
    for (int k = 0; k < NH; ++k)
        acc += hrow[k] * Wd1[(size_t)k * NHD + n];
    hid[(size_t)b * NHD + n] = fmaxf(acc, 0.0f);
}

// out = [hid | actions | horizon] @ Wd2 + bd2   K = 512 + 64 + 1 = 577
__global__ void head2(const float* __restrict__ hid, const float* __restrict__ act,
                      const float* __restrict__ hor, const float* __restrict__ Wd2,
                      const float* __restrict__ bd2, float* __restrict__ out)
{
    int b = blockIdx.x;
    int n = threadIdx.x;
    float acc = bd2[n];
    const float* hrow = hid + (size_t)b * NHD;
    #pragma unroll 4
    for (int k = 0; k < NHD; ++k) acc += hrow[k] * Wd2[(size_t)k * NO + n];
    const float* arow = act + (size_t)b * NA;
    #pragma unroll
    for (int k = 0; k < NA; ++k) acc += arow[k] * Wd2[(size_t)(NHD + k) * NO + n];
    acc += hor[b] * Wd2[(size_t)576 * NO + n];
    out[(size_t)b * NO + n] = acc;
}

extern "C" void kernel_launch(void* const* d_in, const int* in_sizes, int n_in,
                              void* d_out, int out_size, void* d_ws, size_t ws_size,
                              hipStream_t stream)
{
    (void)in_sizes; (void)n_in; (void)out_size; (void)ws_size;
    const float* x    = (const float*)d_in[0];
    const float* act  = (const float*)d_in[1];
    const float* hor  = (const float*)d_in[2];
    const float* Wx   = (const float*)d_in[3];
    const float* Wh   = (const float*)d_in[4];
    const float* bias = (const float*)d_in[5];
    const float* Wd1  = (const float*)d_in[6];
    const float* bd1  = (const float*)d_in[7];
    const float* Wd2  = (const float*)d_in[8];
    const float* bd2  = (const float*)d_in[9];
    float* out = (float*)d_out;

    char* wsb = (char*)d_ws;
    unsigned short* hhi = (unsigned short*)(wsb + WS_HHI);
    unsigned short* hlo = (unsigned short*)(wsb + WS_HLO);
    float* hF32 = (float*)(wsb + WS_HF32);
    float* hid  = (float*)(wsb + WS_HID);
    int*   ctr  = (int*)(wsb + WS_CTR);

    prologue<<<256, 256, 0, stream>>>((unsigned int*)(wsb + WS_HHI),
                                      (unsigned int*)(wsb + WS_HLO),
                                      (unsigned int*)(wsb + WS_CTR));

    // Plain launch (NOT cooperative — see r2 post-mortem). 256 blocks == 256 CUs.
    lstm_persist<<<dim3(256), dim3(256), 0, stream>>>(x, Wx, Wh, bias,
                                                      hhi, hlo, hF32, ctr);

    head1<<<128, 256, 0, stream>>>(hF32, Wd1, bd1, hid);
    head2<<<64, 64, 0, stream>>>(hid, act, hor, Wd2, bd2, out);
}

// Round 4
// 4691.056 us; speedup vs baseline: 1.2599x; 1.2599x over previous
//
#include <hip/hip_runtime.h>
#include <stdint.h>

// Problem dims
#define NB   64      // batch
#define NT   256     // timesteps
#define NS   512     // input feature (state)
#define NH   1024    // hidden
#define NG   4096    // 4*NH (gates)
#define NHD  512     // dense1 width
#define NA   64      // action size
#define NO   64      // n_output

typedef float f32x4  __attribute__((ext_vector_type(4)));
typedef short bf16x8 __attribute__((ext_vector_type(8)));

__device__ __forceinline__ unsigned short f2bf(float f) {
    union { float f; unsigned u; } a; a.f = f;
    unsigned u = a.u;
    return (unsigned short)((u + 0x7fffu + ((u >> 16) & 1u)) >> 16);   // RNE
}
__device__ __forceinline__ float bf2f(unsigned short h) {
    union { unsigned u; float f; } a; a.u = ((unsigned)h) << 16; return a.f;
}
__device__ __forceinline__ float sigm(float x) { return 1.0f / (1.0f + expf(-x)); }

// Workspace layout (bytes):
//   [0)       hhi : 2 x 64 x 1024 bf16 = 262144   (h high bf16, double-buffered)
//   [262144)  hlo : 2 x 64 x 1024 bf16 = 262144   (h residual bf16)
//   [524288)  hF32: 64 x 1024 f32      = 262144
//   [786432)  hid : 64 x 512 f32       = 131072
//   [917504)  flags: 2 groups x 128 ints = 1024
#define WS_HHI   0
#define WS_HLO   262144
#define WS_HF32  524288
#define WS_HID   786432
#define WS_FLG   917504

__global__ void prologue(unsigned int* __restrict__ hhi32,
                         unsigned int* __restrict__ hlo32,
                         unsigned int* __restrict__ flg32) {
    int idx = blockIdx.x * blockDim.x + threadIdx.x;   // 65536 threads
    hhi32[idx] = 0u;                                    // zero both parities
    hlo32[idx] = 0u;
    if (idx < 256) flg32[idx] = 0u;
}

// Persistent LSTM recurrence, double-bf16 (hi/lo) precision.
// PLAIN launch (cooperative launch fails silently in this harness — r2 post-mortem).
// 256 blocks == 256 CUs, 1 block/CU via __launch_bounds__(256,1): all co-resident.
// Grid: 2 groups x 128 blocks; group g: batches [32g,32g+32) (2 m-tiles);
// block bi: h-cols [8bi,8bi+8) x 4 gates as 2 n-tiles; wave w: K-slice.
// v = hi + lo (two bf16); tile product = 3 MFMAs (hh, hl, lh), fp32 accum.
//
// r4 structure: flag-array barrier (release-store per block, wave0 polls all
// 128 flags — no atomic RMW serialization) + x-path for t+1 computed AFTER
// posting the flag, hiding it under the other blocks' barrier latency.
__global__ __launch_bounds__(256, 1) void lstm_persist(
    const float* __restrict__ x, const float* __restrict__ Wx,
    const float* __restrict__ Wh, const float* __restrict__ bias,
    unsigned short* __restrict__ hhi, unsigned short* __restrict__ hlo,
    float* __restrict__ hF32, int* __restrict__ flags)
{
    const int g    = blockIdx.x >> 7;
    const int bi   = blockIdx.x & 127;
    const int tid  = threadIdx.x;
    const int w    = tid >> 6;
    const int lane = tid & 63;
    const int lm   = lane & 15;   // A: m(batch row) ; B: n ; D: col
    const int lq   = lane >> 4;   // k-quad

    __shared__ float zl[4][2][2][16][17];   // [wave][mt][nt][row][col] (+1 pad)

    // ---- one-time: weight B-fragments (hi/lo bf16) into registers ----
    // B-frag (16x16x32): lane holds B[k = lq*8 + j][n = lm], j = 0..7
    bf16x8 wxh[2][4], wxl[2][4];   // [nt][kstep] x-path, K=512/4waves
    bf16x8 whh[2][8], whl[2][8];   // [nt][kstep] h-path, K=1024/4waves
    #pragma unroll
    for (int nt = 0; nt < 2; ++nt) {
        const int gate = nt * 2 + (lm >> 3);
        const int zc   = gate * NH + bi * 8 + (lm & 7);
        #pragma unroll
        for (int ks = 0; ks < 4; ++ks)
            #pragma unroll
            for (int j = 0; j < 8; ++j) {
                int k = w * 128 + ks * 32 + lq * 8 + j;
                float v = Wx[(size_t)k * NG + zc];
                unsigned short h = f2bf(v);
                wxh[nt][ks][j] = (short)h;
                wxl[nt][ks][j] = (short)f2bf(v - bf2f(h));
            }
        #pragma unroll
        for (int ks = 0; ks < 8; ++ks)
            #pragma unroll
            for (int j = 0; j < 8; ++j) {
                int k = w * 256 + ks * 32 + lq * 8 + j;
                float v = Wh[(size_t)k * NG + zc];
                unsigned short h = f2bf(v);
                whh[nt][ks][j] = (short)h;
                whl[nt][ks][j] = (short)f2bf(v - bf2f(h));
            }
    }

    // ---- per-thread cell state: thread owns (batch, h-col) ----
    const int bloc   = tid >> 3;         // batch-in-group 0..31
    const int hcc    = tid & 7;          // h-col-in-block 0..7
    const int gbatch = g * 32 + bloc;
    const int col    = bi * 8 + hcc;
    const int emt    = bloc >> 4;        // m-tile for LDS read
    const int emr    = bloc & 15;        // row within m-tile
    float bgate[4];
    #pragma unroll
    for (int gt = 0; gt < 4; ++gt) bgate[gt] = bias[gt * NH + col];
    float c = 0.0f;

    int* const gflags = flags + g * 128;
    int* const myflag = gflags + bi;

    // ---- x-path for t=0 into the carried accumulator ----
    f32x4 acc[2][2];
    #pragma unroll
    for (int mt = 0; mt < 2; ++mt)
        #pragma unroll
        for (int nt = 0; nt < 2; ++nt) {
            acc[mt][nt][0] = 0.f; acc[mt][nt][1] = 0.f;
            acc[mt][nt][2] = 0.f; acc[mt][nt][3] = 0.f;
        }
    #pragma unroll
    for (int ks = 0; ks < 4; ++ks) {
        bf16x8 axh[2], axl[2];
        #pragma unroll
        for (int mt = 0; mt < 2; ++mt) {
            const float* xs = x + ((size_t)(g * 32 + mt * 16 + lm) * NT + 0) * NS
                                + w * 128 + ks * 32 + lq * 8;
            const f32x4* p = reinterpret_cast<const f32x4*>(xs);
            f32x4 vlo = p[0], vhi = p[1];
            #pragma unroll
            for (int j = 0; j < 4; ++j) {
                unsigned short h0 = f2bf(vlo[j]);
                axh[mt][j]     = (short)h0;
                axl[mt][j]     = (short)f2bf(vlo[j] - bf2f(h0));
                unsigned short h1 = f2bf(vhi[j]);
                axh[mt][4 + j] = (short)h1;
                axl[mt][4 + j] = (short)f2bf(vhi[j] - bf2f(h1));
            }
        }
        #pragma unroll
        for (int mt = 0; mt < 2; ++mt)
            #pragma unroll
            for (int nt = 0; nt < 2; ++nt) {
                acc[mt][nt] = __builtin_amdgcn_mfma_f32_16x16x32_bf16(axh[mt], wxh[nt][ks], acc[mt][nt], 0, 0, 0);
                acc[mt][nt] = __builtin_amdgcn_mfma_f32_16x16x32_bf16(axh[mt], wxl[nt][ks], acc[mt][nt], 0, 0, 0);
                acc[mt][nt] = __builtin_amdgcn_mfma_f32_16x16x32_bf16(axl[mt], wxh[nt][ks], acc[mt][nt], 0, 0, 0);
            }
    }

    #pragma unroll 1
    for (int t = 0; t < NT; ++t) {
        // ---- wait for h_t: wave0 polls all 128 group flags (2 per lane, 8B) ----
        if (w == 0) {
            const unsigned long long* fp =
                reinterpret_cast<const unsigned long long*>(gflags + lane * 2);
            for (;;) {
                unsigned long long v = __hip_atomic_load(fp, __ATOMIC_RELAXED,
                                                         __HIP_MEMORY_SCOPE_AGENT);
                int f0 = (int)(v & 0xffffffffu);
                int f1 = (int)(v >> 32);
                if (__all(f0 >= t && f1 >= t)) break;
                __builtin_amdgcn_s_sleep(1);
            }
            __threadfence();   // acquire: invalidate L1/L2 before reading fresh h
        }
        __syncthreads();

        // ---- h A-fragments (hi+lo), both m-tiles — issue all loads early ----
        const size_t par = (size_t)(t & 1) * (NB * NH);
        bf16x8 ahh[2][8], ahl[2][8];
        #pragma unroll
        for (int mt = 0; mt < 2; ++mt) {
            const size_t rb = par + (size_t)(g * 32 + mt * 16 + lm) * NH + w * 256 + lq * 8;
            #pragma unroll
            for (int ks = 0; ks < 8; ++ks) {
                ahh[mt][ks] = *reinterpret_cast<const bf16x8*>(hhi + rb + ks * 32);
                ahl[mt][ks] = *reinterpret_cast<const bf16x8*>(hlo + rb + ks * 32);
            }
        }

        // ---- h path: 3-term MFMA into carried acc (holds x-path of step t) ----
        #pragma unroll
        for (int ks = 0; ks < 8; ++ks)
            #pragma unroll
            for (int mt = 0; mt < 2; ++mt)
                #pragma unroll
                for (int nt = 0; nt < 2; ++nt) {
                    acc[mt][nt] = __builtin_amdgcn_mfma_f32_16x16x32_bf16(ahh[mt][ks], whh[nt][ks], acc[mt][nt], 0, 0, 0);
                    acc[mt][nt] = __builtin_amdgcn_mfma_f32_16x16x32_bf16(ahh[mt][ks], whl[nt][ks], acc[mt][nt], 0, 0, 0);
                    acc[mt][nt] = __builtin_amdgcn_mfma_f32_16x16x32_bf16(ahl[mt][ks], whh[nt][ks], acc[mt][nt], 0, 0, 0);
                }

        // ---- cross-wave K-reduction via LDS ----
        // D layout: row = lq*4 + r, col = lm
        #pragma unroll
        for (int mt = 0; mt < 2; ++mt)
            #pragma unroll
            for (int nt = 0; nt < 2; ++nt)
                #pragma unroll
                for (int r = 0; r < 4; ++r)
                    zl[w][mt][nt][lq * 4 + r][lm] = acc[mt][nt][r];
        __syncthreads();

        float zg[4];
        #pragma unroll
        for (int gt = 0; gt < 4; ++gt) {
            const int nt = gt >> 1;
            const int n  = (gt & 1) * 8 + hcc;
            zg[gt] = zl[0][emt][nt][emr][n] + zl[1][emt][nt][emr][n]
                   + zl[2][emt][nt][emr][n] + zl[3][emt][nt][emr][n] + bgate[gt];
        }

        // Keras gate order: i, f, g, o
        float ig = sigm(zg[0]);
        float fg = sigm(zg[1]);
        float gg = tanhf(zg[2]);
        float og = sigm(zg[3]);
        c = fg * c + ig * gg;
        float hv = og * tanhf(c);

        unsigned short hb = f2bf(hv);
        const size_t po = (size_t)((t + 1) & 1) * (NB * NH) + (size_t)gbatch * NH + col;
        hhi[po] = hb;
        hlo[po] = f2bf(hv - bf2f(hb));
        if (t == NT - 1) hF32[(size_t)gbatch * NH + col] = hv;

        // ---- publish h_{t+1}: drain stores (syncthreads waits vmcnt(0)),
        // then release-store this block's flag (no RMW, no serialization) ----
        __syncthreads();
        if (tid == 0)
            __hip_atomic_store(myflag, t + 1, __ATOMIC_RELEASE, __HIP_MEMORY_SCOPE_AGENT);

        // ---- overlap region: x-path for t+1 while other blocks finish ----
        if (t + 1 < NT) {
            #pragma unroll
            for (int mt = 0; mt < 2; ++mt)
                #pragma unroll
                for (int nt = 0; nt < 2; ++nt) {
                    acc[mt][nt][0] = 0.f; acc[mt][nt][1] = 0.f;
                    acc[mt][nt][2] = 0.f; acc[mt][nt][3] = 0.f;
                }
            #pragma unroll
            for (int ks = 0; ks < 4; ++ks) {
                bf16x8 axh[2], axl[2];
                #pragma unroll
                for (int mt = 0; mt < 2; ++mt) {
                    const float* xs = x + ((size_t)(g * 32 + mt * 16 + lm) * NT + (t + 1)) * NS
                                        + w * 128 + ks * 32 + lq * 8;
                    const f32x4* p = reinterpret_cast<const f32x4*>(xs);
                    f32x4 vlo = p[0], vhi = p[1];
                    #pragma unroll
                    for (int j = 0; j < 4; ++j) {
                        unsigned short h0 = f2bf(vlo[j]);
                        axh[mt][j]     = (short)h0;
                        axl[mt][j]     = (short)f2bf(vlo[j] - bf2f(h0));
                        unsigned short h1 = f2bf(vhi[j]);
                        axh[mt][4 + j] = (short)h1;
                        axl[mt][4 + j] = (short)f2bf(vhi[j] - bf2f(h1));
                    }
                }
                #pragma unroll
                for (int mt = 0; mt < 2; ++mt)
                    #pragma unroll
                    for (int nt = 0; nt < 2; ++nt) {
                        acc[mt][nt] = __builtin_amdgcn_mfma_f32_16x16x32_bf16(axh[mt], wxh[nt][ks], acc[mt][nt], 0, 0, 0);
                        acc[mt][nt] = __builtin_amdgcn_mfma_f32_16x16x32_bf16(axh[mt], wxl[nt][ks], acc[mt][nt], 0, 0, 0);
                        acc[mt][nt] = __builtin_amdgcn_mfma_f32_16x16x32_bf16(axl[mt], wxh[nt][ks], acc[mt][nt], 0, 0, 0);
                    }
            }
        }
    }
}

// hid = relu(hF32 @ Wd1 + bd1)   [64,1024]x[1024,512]
__global__ void head1(const float* __restrict__ hF32, const float* __restrict__ Wd1,
                      const float* __restrict__ bd1, float* __restrict__ hid)
{
    int b = blockIdx.x >> 1;
    int n = (blockIdx.x & 1) * 256 + threadIdx.x;
    const float* hrow = hF32 + (size_t)b * NH;
    float acc = bd1[n];
    #pragma unroll 4
    for (int k = 0; k < NH; ++k)
        acc += hrow[k] * Wd1[(size_t)k * NHD + n];
    hid[(size_t)b * NHD + n] = fmaxf(acc, 0.0f);
}

// out = [hid | actions | horizon] @ Wd2 + bd2   K = 512 + 64 + 1 = 577
__global__ void head2(const float* __restrict__ hid, const float* __restrict__ act,
                      const float* __restrict__ hor, const float* __restrict__ Wd2,
                      const float* __restrict__ bd2, float* __restrict__ out)
{
    int b = blockIdx.x;
    int n = threadIdx.x;
    float acc = bd2[n];
    const float* hrow = hid + (size_t)b * NHD;
    #pragma unroll 4
    for (int k = 0; k < NHD; ++k) acc += hrow[k] * Wd2[(size_t)k * NO + n];
    const float* arow = act + (size_t)b * NA;
    #pragma unroll
    for (int k = 0; k < NA; ++k) acc += arow[k] * Wd2[(size_t)(NHD + k) * NO + n];
    acc += hor[b] * Wd2[(size_t)576 * NO + n];
    out[(size_t)b * NO + n] = acc;
}

extern "C" void kernel_launch(void* const* d_in, const int* in_sizes, int n_in,
                              void* d_out, int out_size, void* d_ws, size_t ws_size,
                              hipStream_t stream)
{
    (void)in_sizes; (void)n_in; (void)out_size; (void)ws_size;
    const float* x    = (const float*)d_in[0];
    const float* act  = (const float*)d_in[1];
    const float* hor  = (const float*)d_in[2];
    const float* Wx   = (const float*)d_in[3];
    const float* Wh   = (const float*)d_in[4];
    const float* bias = (const float*)d_in[5];
    const float* Wd1  = (const float*)d_in[6];
    const float* bd1  = (const float*)d_in[7];
    const float* Wd2  = (const float*)d_in[8];
    const float* bd2  = (const float*)d_in[9];
    float* out = (float*)d_out;

    char* wsb = (char*)d_ws;
    unsigned short* hhi = (unsigned short*)(wsb + WS_HHI);
    unsigned short* hlo = (unsigned short*)(wsb + WS_HLO);
    float* hF32 = (float*)(wsb + WS_HF32);
    float* hid  = (float*)(wsb + WS_HID);
    int*   flg  = (int*)(wsb + WS_FLG);

    prologue<<<256, 256, 0, stream>>>((unsigned int*)(wsb + WS_HHI),
                                      (unsigned int*)(wsb + WS_HLO),
                                      (unsigned int*)(wsb + WS_FLG));

    // Plain launch (NOT cooperative — see r2 post-mortem). 256 blocks == 256 CUs.
    lstm_persist<<<dim3(256), dim3(256), 0, stream>>>(x, Wx, Wh, bias,
                                                      hhi, hlo, hF32, flg);

    head1<<<128, 256, 0, stream>>>(hF32, Wd1, bd1, hid);
    head2<<<64, 64, 0, stream>>>(hid, act, hor, Wd2, bd2, out);
}

// Round 5
// 3322.917 us; speedup vs baseline: 1.7786x; 1.4117x over previous
//
#include <hip/hip_runtime.h>
#include <stdint.h>

// Problem dims
#define NB   64      // batch
#define NT   256     // timesteps
#define NS   512     // input feature (state)
#define NH   1024    // hidden
#define NG   4096    // 4*NH (gates)
#define NHD  512     // dense1 width
#define NA   64      // action size
#define NO   64      // n_output

typedef float f32x4  __attribute__((ext_vector_type(4)));
typedef short bf16x8 __attribute__((ext_vector_type(8)));
typedef int   i32x4  __attribute__((ext_vector_type(4)));

__device__ __forceinline__ unsigned short f2bf(float f) {
    union { float f; unsigned u; } a; a.f = f;
    unsigned u = a.u;
    return (unsigned short)((u + 0x7fffu + ((u >> 16) & 1u)) >> 16);   // RNE
}
__device__ __forceinline__ float bf2f(unsigned short h) {
    union { unsigned u; float f; } a; a.u = ((unsigned)h) << 16; return a.f;
}
__device__ __forceinline__ float sigm(float x) {
    return __fdividef(1.0f, 1.0f + __expf(-x));
}
__device__ __forceinline__ float tanh_f(float x) {
    float e = __expf(-2.0f * fabsf(x));
    float r = __fdividef(1.0f - e, 1.0f + e);
    return x >= 0.0f ? r : -r;
}

// Workspace layout (bytes):
//   [0)       hpack: 2 x 64 x 1024 u32 = 524288  (h as (hi|lo<<16), dbl-buffered)
//   [524288)  hF32 : 64 x 1024 f32     = 262144
//   [786432)  hid  : 64 x 512 f32      = 131072
//   [917504)  flags: 2 groups x 128 i32 = 1024
#define WS_HPK   0
#define WS_HF32  524288
#define WS_HID   786432
#define WS_FLG   917504

__global__ void prologue(unsigned int* __restrict__ hpk32,
                         unsigned int* __restrict__ flg32) {
    int idx = blockIdx.x * blockDim.x + threadIdx.x;   // 65536 threads
    hpk32[idx] = 0u;            // both parities: 131072 u32 total
    hpk32[idx + 65536] = 0u;
    if (idx < 256) flg32[idx] = 0u;
}

// Persistent LSTM recurrence, double-bf16 (hi/lo) precision.
// PLAIN launch (cooperative launch fails silently in this harness — r2 post-mortem).
// 256 blocks == 256 CUs, 1 block/CU via __launch_bounds__(256,1): all co-resident.
// Grid: 2 groups x 128 blocks; group g: batches [32g,32g+32) (2 m-tiles);
// block bi: h-cols [8bi,8bi+8) x 4 gates as 2 n-tiles; wave w: K-slice.
// v = hi + lo (two bf16); tile product = 3 MFMAs (hh, hl, lh), fp32 accum.
//
// r5: FENCE-FREE h exchange. r4 post-mortem: per-step agent release/acquire
// fences (buffer_wbl2 + buffer_inv, full 4MB L2 maintenance x256 blocks x256
// steps) were ~16us/step. Now h is exchanged as packed u32 via RELAXED AGENT
// atomics (per-access coherent, sc1 — bypasses the non-coherent L2), flags
// via relaxed agent atomics; NO threadfence / release fences at all. x stays
// in normal cached loads and now survives in L2 (no invalidation).
__global__ __launch_bounds__(256, 1) void lstm_persist(
    const float* __restrict__ x, const float* __restrict__ Wx,
    const float* __restrict__ Wh, const float* __restrict__ bias,
    unsigned int* __restrict__ hpack, float* __restrict__ hF32,
    int* __restrict__ flags)
{
    const int g    = blockIdx.x >> 7;
    const int bi   = blockIdx.x & 127;
    const int tid  = threadIdx.x;
    const int w    = tid >> 6;
    const int lane = tid & 63;
    const int lm   = lane & 15;   // A: m(batch row) ; B: n ; D: col
    const int lq   = lane >> 4;   // k-quad

    __shared__ float zl[4][2][2][16][17];   // [wave][mt][nt][row][col] (+1 pad)

    // ---- one-time: weight B-fragments (hi/lo bf16) into registers ----
    // B-frag (16x16x32): lane holds B[k = lq*8 + j][n = lm], j = 0..7
    bf16x8 wxh[2][4], wxl[2][4];   // [nt][kstep] x-path, K=512/4waves
    bf16x8 whh[2][8], whl[2][8];   // [nt][kstep] h-path, K=1024/4waves
    #pragma unroll
    for (int nt = 0; nt < 2; ++nt) {
        const int gate = nt * 2 + (lm >> 3);
        const int zc   = gate * NH + bi * 8 + (lm & 7);
        #pragma unroll
        for (int ks = 0; ks < 4; ++ks)
            #pragma unroll
            for (int j = 0; j < 8; ++j) {
                int k = w * 128 + ks * 32 + lq * 8 + j;
                float v = Wx[(size_t)k * NG + zc];
                unsigned short h = f2bf(v);
                wxh[nt][ks][j] = (short)h;
                wxl[nt][ks][j] = (short)f2bf(v - bf2f(h));
            }
        #pragma unroll
        for (int ks = 0; ks < 8; ++ks)
            #pragma unroll
            for (int j = 0; j < 8; ++j) {
                int k = w * 256 + ks * 32 + lq * 8 + j;
                float v = Wh[(size_t)k * NG + zc];
                unsigned short h = f2bf(v);
                whh[nt][ks][j] = (short)h;
                whl[nt][ks][j] = (short)f2bf(v - bf2f(h));
            }
    }

    // ---- per-thread cell state: thread owns (batch, h-col) ----
    const int bloc   = tid >> 3;         // batch-in-group 0..31
    const int hcc    = tid & 7;          // h-col-in-block 0..7
    const int gbatch = g * 32 + bloc;
    const int col    = bi * 8 + hcc;
    const int emt    = bloc >> 4;        // m-tile for LDS read
    const int emr    = bloc & 15;        // row within m-tile
    float bgate[4];
    #pragma unroll
    for (int gt = 0; gt < 4; ++gt) bgate[gt] = bias[gt * NH + col];
    float c = 0.0f;

    int* const gflags = flags + g * 128;
    int* const myflag = gflags + bi;

    // ---- x-path for t=0 into the carried accumulator ----
    f32x4 acc[2][2];
    #pragma unroll
    for (int mt = 0; mt < 2; ++mt)
        #pragma unroll
        for (int nt = 0; nt < 2; ++nt) {
            acc[mt][nt][0] = 0.f; acc[mt][nt][1] = 0.f;
            acc[mt][nt][2] = 0.f; acc[mt][nt][3] = 0.f;
        }
    #pragma unroll
    for (int ks = 0; ks < 4; ++ks) {
        bf16x8 axh[2], axl[2];
        #pragma unroll
        for (int mt = 0; mt < 2; ++mt) {
            const float* xs = x + ((size_t)(g * 32 + mt * 16 + lm) * NT + 0) * NS
                                + w * 128 + ks * 32 + lq * 8;
            const f32x4* p = reinterpret_cast<const f32x4*>(xs);
            f32x4 vlo = p[0], vhi = p[1];
            #pragma unroll
            for (int j = 0; j < 4; ++j) {
                unsigned short h0 = f2bf(vlo[j]);
                axh[mt][j]     = (short)h0;
                axl[mt][j]     = (short)f2bf(vlo[j] - bf2f(h0));
                unsigned short h1 = f2bf(vhi[j]);
                axh[mt][4 + j] = (short)h1;
                axl[mt][4 + j] = (short)f2bf(vhi[j] - bf2f(h1));
            }
        }
        #pragma unroll
        for (int mt = 0; mt < 2; ++mt)
            #pragma unroll
            for (int nt = 0; nt < 2; ++nt) {
                acc[mt][nt] = __builtin_amdgcn_mfma_f32_16x16x32_bf16(axh[mt], wxh[nt][ks], acc[mt][nt], 0, 0, 0);
                acc[mt][nt] = __builtin_amdgcn_mfma_f32_16x16x32_bf16(axh[mt], wxl[nt][ks], acc[mt][nt], 0, 0, 0);
                acc[mt][nt] = __builtin_amdgcn_mfma_f32_16x16x32_bf16(axl[mt], wxh[nt][ks], acc[mt][nt], 0, 0, 0);
            }
    }

    #pragma unroll 1
    for (int t = 0; t < NT; ++t) {
        // ---- wait for h_t: wave0 polls all 128 group flags (2/lane, 8B atomic) ----
        if (w == 0) {
            const unsigned long long* fp =
                reinterpret_cast<const unsigned long long*>(gflags + lane * 2);
            for (;;) {
                unsigned long long v = __hip_atomic_load(fp, __ATOMIC_RELAXED,
                                                         __HIP_MEMORY_SCOPE_AGENT);
                int f0 = (int)(v & 0xffffffffu);
                int f1 = (int)(v >> 32);
                if (__all(f0 >= t && f1 >= t)) break;
                __builtin_amdgcn_s_sleep(1);
            }
            // no fence: h loads below are agent-scope (coherent past L2)
        }
        __syncthreads();

        // ---- h A-fragments: 8B agent-atomic loads of packed (hi|lo) ----
        const size_t par = (size_t)(t & 1) * (NB * NH);
        unsigned long long q[2][8][4];
        #pragma unroll
        for (int mt = 0; mt < 2; ++mt) {
            const size_t rb = par + (size_t)(g * 32 + mt * 16 + lm) * NH + w * 256 + lq * 8;
            #pragma unroll
            for (int ks = 0; ks < 8; ++ks) {
                const unsigned long long* hp =
                    reinterpret_cast<const unsigned long long*>(hpack + rb + ks * 32);
                #pragma unroll
                for (int i = 0; i < 4; ++i)
                    q[mt][ks][i] = __hip_atomic_load(hp + i, __ATOMIC_RELAXED,
                                                     __HIP_MEMORY_SCOPE_AGENT);
            }
        }
        // unpack: u32 = hi | (lo<<16); build bf16x8 hi-frag and lo-frag
        bf16x8 ahh[2][8], ahl[2][8];
        #pragma unroll
        for (int mt = 0; mt < 2; ++mt)
            #pragma unroll
            for (int ks = 0; ks < 8; ++ks) {
                i32x4 hh, hl;
                #pragma unroll
                for (int i = 0; i < 4; ++i) {
                    unsigned u0 = (unsigned)(q[mt][ks][i] & 0xffffffffu);
                    unsigned u1 = (unsigned)(q[mt][ks][i] >> 32);
                    hh[i] = (int)((u0 & 0xffffu) | (u1 << 16));
                    hl[i] = (int)((u0 >> 16) | (u1 & 0xffff0000u));
                }
                union { i32x4 i; bf16x8 v; } ch, cl;
                ch.i = hh; cl.i = hl;
                ahh[mt][ks] = ch.v;
                ahl[mt][ks] = cl.v;
            }

        // ---- h path: 3-term MFMA into carried acc (holds x-path of step t) ----
        #pragma unroll
        for (int ks = 0; ks < 8; ++ks)
            #pragma unroll
            for (int mt = 0; mt < 2; ++mt)
                #pragma unroll
                for (int nt = 0; nt < 2; ++nt) {
                    acc[mt][nt] = __builtin_amdgcn_mfma_f32_16x16x32_bf16(ahh[mt][ks], whh[nt][ks], acc[mt][nt], 0, 0, 0);
                    acc[mt][nt] = __builtin_amdgcn_mfma_f32_16x16x32_bf16(ahh[mt][ks], whl[nt][ks], acc[mt][nt], 0, 0, 0);
                    acc[mt][nt] = __builtin_amdgcn_mfma_f32_16x16x32_bf16(ahl[mt][ks], whh[nt][ks], acc[mt][nt], 0, 0, 0);
                }

        // ---- cross-wave K-reduction via LDS ----
        // D layout: row = lq*4 + r, col = lm
        #pragma unroll
        for (int mt = 0; mt < 2; ++mt)
            #pragma unroll
            for (int nt = 0; nt < 2; ++nt)
                #pragma unroll
                for (int r = 0; r < 4; ++r)
                    zl[w][mt][nt][lq * 4 + r][lm] = acc[mt][nt][r];
        __syncthreads();

        float zg[4];
        #pragma unroll
        for (int gt = 0; gt < 4; ++gt) {
            const int nt = gt >> 1;
            const int n  = (gt & 1) * 8 + hcc;
            zg[gt] = zl[0][emt][nt][emr][n] + zl[1][emt][nt][emr][n]
                   + zl[2][emt][nt][emr][n] + zl[3][emt][nt][emr][n] + bgate[gt];
        }

        // Keras gate order: i, f, g, o
        float ig = sigm(zg[0]);
        float fg = sigm(zg[1]);
        float gg = tanh_f(zg[2]);
        float og = sigm(zg[3]);
        c = fg * c + ig * gg;
        float hv = og * tanh_f(c);

        unsigned short hb = f2bf(hv);
        unsigned short lb = f2bf(hv - bf2f(hb));
        unsigned pk = (unsigned)hb | ((unsigned)lb << 16);
        const size_t po = (size_t)((t + 1) & 1) * (NB * NH) + (size_t)gbatch * NH + col;
        __hip_atomic_store(hpack + po, pk, __ATOMIC_RELAXED, __HIP_MEMORY_SCOPE_AGENT);
        if (t == NT - 1) hF32[(size_t)gbatch * NH + col] = hv;

        // ---- publish: __syncthreads drains every wave's vmcnt (atomic stores
        // complete at coherence point), then relaxed flag store — no fences ----
        __syncthreads();
        if (tid == 0)
            __hip_atomic_store(myflag, t + 1, __ATOMIC_RELAXED, __HIP_MEMORY_SCOPE_AGENT);

        // ---- overlap region: x-path for t+1 while other blocks finish ----
        if (t + 1 < NT) {
            #pragma unroll
            for (int mt = 0; mt < 2; ++mt)
                #pragma unroll
                for (int nt = 0; nt < 2; ++nt) {
                    acc[mt][nt][0] = 0.f; acc[mt][nt][1] = 0.f;
                    acc[mt][nt][2] = 0.f; acc[mt][nt][3] = 0.f;
                }
            #pragma unroll
            for (int ks = 0; ks < 4; ++ks) {
                bf16x8 axh[2], axl[2];
                #pragma unroll
                for (int mt = 0; mt < 2; ++mt) {
                    const float* xs = x + ((size_t)(g * 32 + mt * 16 + lm) * NT + (t + 1)) * NS
                                        + w * 128 + ks * 32 + lq * 8;
                    const f32x4* p = reinterpret_cast<const f32x4*>(xs);
                    f32x4 vlo = p[0], vhi = p[1];
                    #pragma unroll
                    for (int j = 0; j < 4; ++j) {
                        unsigned short h0 = f2bf(vlo[j]);
                        axh[mt][j]     = (short)h0;
                        axl[mt][j]     = (short)f2bf(vlo[j] - bf2f(h0));
                        unsigned short h1 = f2bf(vhi[j]);
                        axh[mt][4 + j] = (short)h1;
                        axl[mt][4 + j] = (short)f2bf(vhi[j] - bf2f(h1));
                    }
                }
                #pragma unroll
                for (int mt = 0; mt < 2; ++mt)
                    #pragma unroll
                    for (int nt = 0; nt < 2; ++nt) {
                        acc[mt][nt] = __builtin_amdgcn_mfma_f32_16x16x32_bf16(axh[mt], wxh[nt][ks], acc[mt][nt], 0, 0, 0);
                        acc[mt][nt] = __builtin_amdgcn_mfma_f32_16x16x32_bf16(axh[mt], wxl[nt][ks], acc[mt][nt], 0, 0, 0);
                        acc[mt][nt] = __builtin_amdgcn_mfma_f32_16x16x32_bf16(axl[mt], wxh[nt][ks], acc[mt][nt], 0, 0, 0);
                    }
            }
        }
    }
}

// hid = relu(hF32 @ Wd1 + bd1)   [64,1024]x[1024,512]
__global__ void head1(const float* __restrict__ hF32, const float* __restrict__ Wd1,
                      const float* __restrict__ bd1, float* __restrict__ hid)
{
    int b = blockIdx.x >> 1;
    int n = (blockIdx.x & 1) * 256 + threadIdx.x;
    const float* hrow = hF32 + (size_t)b * NH;
    float acc = bd1[n];
    #pragma unroll 4
    for (int k = 0; k < NH; ++k)
        acc += hrow[k] * Wd1[(size_t)k * NHD + n];
    hid[(size_t)b * NHD + n] = fmaxf(acc, 0.0f);
}

// out = [hid | actions | horizon] @ Wd2 + bd2   K = 512 + 64 + 1 = 577
__global__ void head2(const float* __restrict__ hid, const float* __restrict__ act,
                      const float* __restrict__ hor, const float* __restrict__ Wd2,
                      const float* __restrict__ bd2, float* __restrict__ out)
{
    int b = blockIdx.x;
    int n = threadIdx.x;
    float acc = bd2[n];
    const float* hrow = hid + (size_t)b * NHD;
    #pragma unroll 4
    for (int k = 0; k < NHD; ++k) acc += hrow[k] * Wd2[(size_t)k * NO + n];
    const float* arow = act + (size_t)b * NA;
    #pragma unroll
    for (int k = 0; k < NA; ++k) acc += arow[k] * Wd2[(size_t)(NHD + k) * NO + n];
    acc += hor[b] * Wd2[(size_t)576 * NO + n];
    out[(size_t)b * NO + n] = acc;
}

extern "C" void kernel_launch(void* const* d_in, const int* in_sizes, int n_in,
                              void* d_out, int out_size, void* d_ws, size_t ws_size,
                              hipStream_t stream)
{
    (void)in_sizes; (void)n_in; (void)out_size; (void)ws_size;
    const float* x    = (const float*)d_in[0];
    const float* act  = (const float*)d_in[1];
    const float* hor  = (const float*)d_in[2];
    const float* Wx   = (const float*)d_in[3];
    const float* Wh   = (const float*)d_in[4];
    const float* bias = (const float*)d_in[5];
    const float* Wd1  = (const float*)d_in[6];
    const float* bd1  = (const float*)d_in[7];
    const float* Wd2  = (const float*)d_in[8];
    const float* bd2  = (const float*)d_in[9];
    float* out = (float*)d_out;

    char* wsb = (char*)d_ws;
    unsigned int* hpk = (unsigned int*)(wsb + WS_HPK);
    float* hF32 = (float*)(wsb + WS_HF32);
    float* hid  = (float*)(wsb + WS_HID);
    int*   flg  = (int*)(wsb + WS_FLG);

    prologue<<<256, 256, 0, stream>>>(hpk, (unsigned int*)(wsb + WS_FLG));

    // Plain launch (NOT cooperative — see r2 post-mortem). 256 blocks == 256 CUs.
    lstm_persist<<<dim3(256), dim3(256), 0, stream>>>(x, Wx, Wh, bias,
                                                      hpk, hF32, flg);

    head1<<<128, 256, 0, stream>>>(hF32, Wd1, bd1, hid);
    head2<<<64, 64, 0, stream>>>(hid, act, hor, Wd2, bd2, out);
}

// Round 8
// 2397.187 us; speedup vs baseline: 2.4655x; 1.3862x over previous
//
#include <hip/hip_runtime.h>
#include <stdint.h>

// Problem dims
#define NB   64      // batch
#define NT   256     // timesteps
#define NS   512     // input feature (state)
#define NH   1024    // hidden
#define NG   4096    // 4*NH (gates)
#define NHD  512     // dense1 width
#define NA   64      // action size
#define NO   64      // n_output

typedef float f32x4  __attribute__((ext_vector_type(4)));
typedef short bf16x8 __attribute__((ext_vector_type(8)));
typedef int   i32x4  __attribute__((ext_vector_type(4)));

__device__ __forceinline__ unsigned short f2bf(float f) {
    union { float f; unsigned u; } a; a.f = f;
    unsigned u = a.u;
    return (unsigned short)((u + 0x7fffu + ((u >> 16) & 1u)) >> 16);   // RNE
}
__device__ __forceinline__ float bf2f(unsigned short h) {
    union { unsigned u; float f; } a; a.u = ((unsigned)h) << 16; return a.f;
}
__device__ __forceinline__ float sigm(float x) {
    return __fdividef(1.0f, 1.0f + __expf(-x));
}
__device__ __forceinline__ float tanh_f(float x) {
    float e = __expf(-2.0f * fabsf(x));
    float r = __fdividef(1.0f - e, 1.0f + e);
    return x >= 0.0f ? r : -r;
}

// sc1 load: bypasses (misses) the non-coherent per-XCD L2 -> reads the
// coherence point. Coalesced 16B/lane, unlike r5's per-8B atomic loads.
#define GLD(dst, base, off) \
    asm volatile("global_load_dwordx4 %0, %1, off offset:" #off " sc1" \
                 : "=v"(dst) : "v"(base) : "memory")
// issue order is ks-major: 4 loads per ks (2 mt x 2 halves)
#define GLD4(ks, o0, o1) \
    GLD(q[ks][0][0], hb0, o0); GLD(q[ks][0][1], hb0, o1); \
    GLD(q[ks][1][0], hb1, o0); GLD(q[ks][1][1], hb1, o1)
// chunked wait: data-tie the chunk's regs so uses can't be hoisted above
#define WAITKS(n, ks) \
    asm volatile("s_waitcnt vmcnt(" #n ")" \
                 : "+v"(q[ks][0][0]), "+v"(q[ks][0][1]), \
                   "+v"(q[ks][1][0]), "+v"(q[ks][1][1]))

// h-phase chunk: wait for chunk ks, unpack (hi|lo<<16), 12 MFMAs.
// NOTE: no #pragma inside a macro body (r6 build failure); the mt/nt loops
// have constant trip count 2 — -O3 fully unrolls them.
#define HKS(WN, ks)                                                              \
    {                                                                            \
        WAITKS(WN, ks);                                                          \
        bf16x8 fh[2], fl[2];                                                     \
        for (int mt = 0; mt < 2; ++mt) {                                         \
            i32x4 qa = q[ks][mt][0], qb = q[ks][mt][1];                          \
            i32x4 hi, lo;                                                        \
            hi[0] = (qa[0] & 0xffff) | (qa[1] << 16);                            \
            lo[0] = (int)(((unsigned)qa[0] >> 16) | ((unsigned)qa[1] & 0xffff0000u)); \
            hi[1] = (qa[2] & 0xffff) | (qa[3] << 16);                            \
            lo[1] = (int)(((unsigned)qa[2] >> 16) | ((unsigned)qa[3] & 0xffff0000u)); \
            hi[2] = (qb[0] & 0xffff) | (qb[1] << 16);                            \
            lo[2] = (int)(((unsigned)qb[0] >> 16) | ((unsigned)qb[1] & 0xffff0000u)); \
            hi[3] = (qb[2] & 0xffff) | (qb[3] << 16);                            \
            lo[3] = (int)(((unsigned)qb[2] >> 16) | ((unsigned)qb[3] & 0xffff0000u)); \
            union { i32x4 i; bf16x8 v; } ch, cl;                                 \
            ch.i = hi; cl.i = lo;                                                \
            fh[mt] = ch.v; fl[mt] = cl.v;                                        \
        }                                                                        \
        for (int mt = 0; mt < 2; ++mt)                                           \
            for (int nt = 0; nt < 2; ++nt) {                                     \
                acc[mt][nt] = __builtin_amdgcn_mfma_f32_16x16x32_bf16(fh[mt], whh[nt][ks], acc[mt][nt], 0, 0, 0); \
                acc[mt][nt] = __builtin_amdgcn_mfma_f32_16x16x32_bf16(fh[mt], whl[nt][ks], acc[mt][nt], 0, 0, 0); \
                acc[mt][nt] = __builtin_amdgcn_mfma_f32_16x16x32_bf16(fl[mt], whh[nt][ks], acc[mt][nt], 0, 0, 0); \
            }                                                                    \
    }

// Workspace layout (bytes):
//   [0)       hpack: 2 x 64 x 1024 u32 = 524288  (h as (hi|lo<<16), dbl-buffered)
//   [524288)  hF32 : 64 x 1024 f32     = 262144
//   [786432)  hid  : 64 x 512 f32      = 131072
//   [917504)  flags: 2 groups x 128 i32 = 1024
#define WS_HPK   0
#define WS_HF32  524288
#define WS_HID   786432
#define WS_FLG   917504

__global__ void prologue(unsigned int* __restrict__ hpk32,
                         unsigned int* __restrict__ flg32) {
    int idx = blockIdx.x * blockDim.x + threadIdx.x;   // 65536 threads
    hpk32[idx] = 0u;            // both parities: 131072 u32 total
    hpk32[idx + 65536] = 0u;
    if (idx < 256) flg32[idx] = 0u;
}

// Persistent LSTM recurrence, double-bf16 (hi/lo) precision.
// PLAIN launch (cooperative fails silently here — r2 post-mortem). 256 blocks
// == 256 CUs, 1 block/CU via __launch_bounds__(256,1): all co-resident.
// 2 groups x 128 blocks; group g: batches [32g,32g+32) (2 m-tiles); block bi:
// h-cols [8bi,8bi+8) x 4 gates as 2 n-tiles; wave w: K-slice. v = hi + lo
// (two bf16); tile product = 3 MFMAs (hh, hl, lh), fp32 accum.
//
// r8 = r7 + the missing "+ lq*8" in the h-burst base (r7 post-mortem: all 4
// k-quads read lq=0's slice -> absmax 0.47). Pipeline: x_{t+1} loads issued
// BEFORE the poll; post-poll h sc1-dwordx4 burst; x-convert + 48 x-MFMAs in
// the h-load shadow; chunked vmcnt waits overlap unpack+h-MFMA w/ load tail.
__global__ __launch_bounds__(256, 1) void lstm_persist(
    const float* __restrict__ x, const float* __restrict__ Wx,
    const float* __restrict__ Wh, const float* __restrict__ bias,
    unsigned int* __restrict__ hpack, float* __restrict__ hF32,
    int* __restrict__ flags)
{
    const int g    = blockIdx.x >> 7;
    const int bi   = blockIdx.x & 127;
    const int tid  = threadIdx.x;
    const int w    = tid >> 6;
    const int lane = tid & 63;
    const int lm   = lane & 15;   // A: m(batch row) ; B: n ; D: col
    const int lq   = lane >> 4;   // k-quad

    __shared__ float zl[4][2][2][16][17];   // [wave][mt][nt][row][col] (+1 pad)

    // ---- one-time: weight B-fragments (hi/lo bf16) into registers ----
    // B-frag (16x16x32): lane holds B[k = lq*8 + j][n = lm], j = 0..7
    bf16x8 wxh[2][4], wxl[2][4];   // [nt][kstep] x-path, K=512/4waves
    bf16x8 whh[2][8], whl[2][8];   // [nt][kstep] h-path, K=1024/4waves
    #pragma unroll
    for (int nt = 0; nt < 2; ++nt) {
        const int gate = nt * 2 + (lm >> 3);
        const int zc   = gate * NH + bi * 8 + (lm & 7);
        #pragma unroll
        for (int ks = 0; ks < 4; ++ks)
            #pragma unroll
            for (int j = 0; j < 8; ++j) {
                int k = w * 128 + ks * 32 + lq * 8 + j;
                float v = Wx[(size_t)k * NG + zc];
                unsigned short h = f2bf(v);
                wxh[nt][ks][j] = (short)h;
                wxl[nt][ks][j] = (short)f2bf(v - bf2f(h));
            }
        #pragma unroll
        for (int ks = 0; ks < 8; ++ks)
            #pragma unroll
            for (int j = 0; j < 8; ++j) {
                int k = w * 256 + ks * 32 + lq * 8 + j;
                float v = Wh[(size_t)k * NG + zc];
                unsigned short h = f2bf(v);
                whh[nt][ks][j] = (short)h;
                whl[nt][ks][j] = (short)f2bf(v - bf2f(h));
            }
    }

    // ---- per-thread cell state: thread owns (batch, h-col) ----
    const int bloc   = tid >> 3;         // batch-in-group 0..31
    const int hcc    = tid & 7;          // h-col-in-block 0..7
    const int gbatch = g * 32 + bloc;
    const int col    = bi * 8 + hcc;
    const int emt    = bloc >> 4;        // m-tile for LDS read
    const int emr    = bloc & 15;        // row within m-tile
    float bgate[4];
    #pragma unroll
    for (int gt = 0; gt < 4; ++gt) bgate[gt] = bias[gt * NH + col];
    float c = 0.0f;

    int* const gflags = flags + g * 128;
    int* const myflag = gflags + bi;

    // x fragments raw fp32, loaded one step ahead: [mt][ks][half]
    f32x4 xr[2][4][2];
    #pragma unroll
    for (int mt = 0; mt < 2; ++mt) {
        const float* xs = x + (size_t)(g * 32 + mt * 16 + lm) * NT * NS
                            + w * 128 + lq * 8;
        #pragma unroll
        for (int ks = 0; ks < 4; ++ks) {
            const f32x4* p = reinterpret_cast<const f32x4*>(xs + ks * 32);
            xr[mt][ks][0] = p[0];
            xr[mt][ks][1] = p[1];
        }
    }

    #pragma unroll 1
    for (int t = 0; t < NT; ++t) {
        // ---- wait for h_t: wave0 polls all 128 group flags (2/lane, 8B atomic).
        // Poll's per-iteration waitcnt also drains the prefetched x loads. ----
        if (w == 0) {
            const unsigned long long* fp =
                reinterpret_cast<const unsigned long long*>(gflags + lane * 2);
            for (;;) {
                unsigned long long v = __hip_atomic_load(fp, __ATOMIC_RELAXED,
                                                         __HIP_MEMORY_SCOPE_AGENT);
                int f0 = (int)(v & 0xffffffffu);
                int f1 = (int)(v >> 32);
                if (__all(f0 >= t && f1 >= t)) break;
                __builtin_amdgcn_s_sleep(1);
            }
            // no fence: h loads below are sc1 (coherent past L2)
        }
        __syncthreads();   // compiler drains vmcnt(0) here for every wave

        // ---- issue h sc1 load burst: 32 x dwordx4, ks-major ----
        // per-lane base includes lq*8 (r7 bug: this term was missing)
        const size_t par = (size_t)(t & 1) * (NB * NH);
        i32x4 q[8][2][2];   // [ks][mt][half]
        const unsigned int* hb0 = hpack + par + (size_t)(g * 32 + lm) * NH
                                + w * 256 + lq * 8;
        const unsigned int* hb1 = hb0 + (size_t)16 * NH;
        GLD4(0, 0, 16);    GLD4(1, 128, 144); GLD4(2, 256, 272); GLD4(3, 384, 400);
        GLD4(4, 512, 528); GLD4(5, 640, 656); GLD4(6, 768, 784); GLD4(7, 896, 912);

        // ---- x-phase in the h-load shadow: convert + 48 MFMAs ----
        f32x4 acc[2][2];
        #pragma unroll
        for (int mt = 0; mt < 2; ++mt)
            #pragma unroll
            for (int nt = 0; nt < 2; ++nt) {
                acc[mt][nt][0] = 0.f; acc[mt][nt][1] = 0.f;
                acc[mt][nt][2] = 0.f; acc[mt][nt][3] = 0.f;
            }
        #pragma unroll
        for (int ks = 0; ks < 4; ++ks) {
            bf16x8 axh[2], axl[2];
            #pragma unroll
            for (int mt = 0; mt < 2; ++mt) {
                f32x4 vlo = xr[mt][ks][0], vhi = xr[mt][ks][1];
                #pragma unroll
                for (int j = 0; j < 4; ++j) {
                    unsigned short h0 = f2bf(vlo[j]);
                    axh[mt][j]     = (short)h0;
                    axl[mt][j]     = (short)f2bf(vlo[j] - bf2f(h0));
                    unsigned short h1 = f2bf(vhi[j]);
                    axh[mt][4 + j] = (short)h1;
                    axl[mt][4 + j] = (short)f2bf(vhi[j] - bf2f(h1));
                }
            }
            #pragma unroll
            for (int mt = 0; mt < 2; ++mt)
                #pragma unroll
                for (int nt = 0; nt < 2; ++nt) {
                    acc[mt][nt] = __builtin_amdgcn_mfma_f32_16x16x32_bf16(axh[mt], wxh[nt][ks], acc[mt][nt], 0, 0, 0);
                    acc[mt][nt] = __builtin_amdgcn_mfma_f32_16x16x32_bf16(axh[mt], wxl[nt][ks], acc[mt][nt], 0, 0, 0);
                    acc[mt][nt] = __builtin_amdgcn_mfma_f32_16x16x32_bf16(axl[mt], wxh[nt][ks], acc[mt][nt], 0, 0, 0);
                }
        }

        // ---- h-phase: chunked waits, unpack, 3-term MFMAs ----
        HKS(28, 0) HKS(24, 1) HKS(20, 2) HKS(16, 3)
        HKS(12, 4) HKS(8, 5)  HKS(4, 6)  HKS(0, 7)

        // ---- cross-wave K-reduction via LDS (D: row = lq*4+r, col = lm) ----
        #pragma unroll
        for (int mt = 0; mt < 2; ++mt)
            #pragma unroll
            for (int nt = 0; nt < 2; ++nt)
                #pragma unroll
                for (int r = 0; r < 4; ++r)
                    zl[w][mt][nt][lq * 4 + r][lm] = acc[mt][nt][r];
        __syncthreads();

        float zg[4];
        #pragma unroll
        for (int gt = 0; gt < 4; ++gt) {
            const int nt = gt >> 1;
            const int n  = (gt & 1) * 8 + hcc;
            zg[gt] = zl[0][emt][nt][emr][n] + zl[1][emt][nt][emr][n]
                   + zl[2][emt][nt][emr][n] + zl[3][emt][nt][emr][n] + bgate[gt];
        }

        // Keras gate order: i, f, g, o
        float ig = sigm(zg[0]);
        float fg = sigm(zg[1]);
        float gg = tanh_f(zg[2]);
        float og = sigm(zg[3]);
        c = fg * c + ig * gg;
        float hv = og * tanh_f(c);

        unsigned short hb = f2bf(hv);
        unsigned short lb = f2bf(hv - bf2f(hb));
        unsigned pk = (unsigned)hb | ((unsigned)lb << 16);
        const size_t po = (size_t)((t + 1) & 1) * (NB * NH) + (size_t)gbatch * NH + col;
        __hip_atomic_store(hpack + po, pk, __ATOMIC_RELAXED, __HIP_MEMORY_SCOPE_AGENT);
        if (t == NT - 1) hF32[(size_t)gbatch * NH + col] = hv;

        // ---- publish: __syncthreads drains every wave's vmcnt (h stores at
        // coherence point), then relaxed flag store — no fences ----
        __syncthreads();
        if (tid == 0)
            __hip_atomic_store(myflag, t + 1, __ATOMIC_RELAXED, __HIP_MEMORY_SCOPE_AGENT);

        // ---- prefetch x_{t+1}: issue BEFORE next poll; loads fly during the
        // spin and are drained by the poll/syncthreads waits ----
        if (t + 1 < NT) {
            #pragma unroll
            for (int mt = 0; mt < 2; ++mt) {
                const float* xs = x + ((size_t)(g * 32 + mt * 16 + lm) * NT + (t + 1)) * NS
                                    + w * 128 + lq * 8;
                #pragma unroll
                for (int ks = 0; ks < 4; ++ks) {
                    const f32x4* p = reinterpret_cast<const f32x4*>(xs + ks * 32);
                    xr[mt][ks][0] = p[0];
                    xr[mt][ks][1] = p[1];
                }
            }
        }
    }
}

// hid = relu(hF32 @ Wd1 + bd1)   [64,1024]x[1024,512]
__global__ void head1(const float* __restrict__ hF32, const float* __restrict__ Wd1,
                      const float* __restrict__ bd1, float* __restrict__ hid)
{
    int b = blockIdx.x >> 1;
    int n = (blockIdx.x & 1) * 256 + threadIdx.x;
    const float* hrow = hF32 + (size_t)b * NH;
    float acc = bd1[n];
    #pragma unroll 4
    for (int k = 0; k < NH; ++k)
        acc += hrow[k] * Wd1[(size_t)k * NHD + n];
    hid[(size_t)b * NHD + n] = fmaxf(acc, 0.0f);
}

// out = [hid | actions | horizon] @ Wd2 + bd2   K = 512 + 64 + 1 = 577
__global__ void head2(const float* __restrict__ hid, const float* __restrict__ act,
                      const float* __restrict__ hor, const float* __restrict__ Wd2,
                      const float* __restrict__ bd2, float* __restrict__ out)
{
    int b = blockIdx.x;
    int n = threadIdx.x;
    float acc = bd2[n];
    const float* hrow = hid + (size_t)b * NHD;
    #pragma unroll 4
    for (int k = 0; k < NHD; ++k) acc += hrow[k] * Wd2[(size_t)k * NO + n];
    const float* arow = act + (size_t)b * NA;
    #pragma unroll
    for (int k = 0; k < NA; ++k) acc += arow[k] * Wd2[(size_t)(NHD + k) * NO + n];
    acc += hor[b] * Wd2[(size_t)576 * NO + n];
    out[(size_t)b * NO + n] = acc;
}

extern "C" void kernel_launch(void* const* d_in, const int* in_sizes, int n_in,
                              void* d_out, int out_size, void* d_ws, size_t ws_size,
                              hipStream_t stream)
{
    (void)in_sizes; (void)n_in; (void)out_size; (void)ws_size;
    const float* x    = (const float*)d_in[0];
    const float* act  = (const float*)d_in[1];
    const float* hor  = (const float*)d_in[2];
    const float* Wx   = (const float*)d_in[3];
    const float* Wh   = (const float*)d_in[4];
    const float* bias = (const float*)d_in[5];
    const float* Wd1  = (const float*)d_in[6];
    const float* bd1  = (const float*)d_in[7];
    const float* Wd2  = (const float*)d_in[8];
    const float* bd2  = (const float*)d_in[9];
    float* out = (float*)d_out;

    char* wsb = (char*)d_ws;
    unsigned int* hpk = (unsigned int*)(wsb + WS_HPK);
    float* hF32 = (float*)(wsb + WS_HF32);
    float* hid  = (float*)(wsb + WS_HID);
    int*   flg  = (int*)(wsb + WS_FLG);

    prologue<<<256, 256, 0, stream>>>(hpk, (unsigned int*)(wsb + WS_FLG));

    // Plain launch (NOT cooperative — see r2 post-mortem). 256 blocks == 256 CUs.
    lstm_persist<<<dim3(256), dim3(256), 0, stream>>>(x, Wx, Wh, bias,
                                                      hpk, hF32, flg);

    head1<<<128, 256, 0, stream>>>(hF32, Wd1, bd1, hid);
    head2<<<64, 64, 0, stream>>>(hid, act, hor, Wd2, bd2, out);
}